// Round 9
// baseline (449.537 us; speedup 1.0000x reference)
//
#include <hip/hip_runtime.h>

#define N_NODES 100000
#define N_EDGES 1600000
#define D_FEAT  128
#define C_CLS   40
#define LN_EPS  1e-5f

#define RPB   256                         // rows per bucket
#define NBKT  ((N_NODES + RPB - 1) / RPB) // 391
#define BCAP  6144                        // padded slots/bucket (mean 4096, sigma~64)
#define TILE_E 4096                       // edges per bin block
#define EBLK  ((N_EDGES + TILE_E - 1) / TILE_E)  // 391
#define CONVB (N_NODES * 64 / 256)        // 25000 conv blocks

typedef __attribute__((ext_vector_type(8))) short short8;
typedef __attribute__((ext_vector_type(4))) float floatx4;

// ---------- bf16 pack/unpack (storage only; accumulate fp32) ----------
__device__ inline unsigned pack_bf2(float x, float y) {
    unsigned xi = __float_as_uint(x);
    unsigned yi = __float_as_uint(y);
    unsigned lo = (xi + 0x7fffu + ((xi >> 16) & 1u)) >> 16;
    unsigned hi = (yi + 0x7fffu + ((yi >> 16) & 1u)) & 0xffff0000u;
    return lo | hi;
}
__device__ inline float bf_lo(unsigned v) { return __uint_as_float(v << 16); }
__device__ inline float bf_hi(unsigned v) { return __uint_as_float(v & 0xffff0000u); }
__device__ inline short bf16_of(float x) {
    unsigned u = __float_as_uint(x);
    return (short)((u + 0x7fffu + ((u >> 16) & 1u)) >> 16);
}

// ---- fused: blocks [0,EBLK) bin edges into buckets; rest convert feat ----
// csr_tmp[b*BCAP + slot] = (lrow<<17) | col
__global__ __launch_bounds__(256) void convbin_k(const float* __restrict__ feat,
                                                 unsigned* __restrict__ hb,
                                                 const int* __restrict__ row,
                                                 const int* __restrict__ col,
                                                 int* __restrict__ bktsz,
                                                 int* __restrict__ csr_tmp) {
    int t = threadIdx.x;
    if (blockIdx.x >= EBLK) {
        int i = (blockIdx.x - EBLK) * 256 + t;       // over N*64
        float2 v = ((const float2*)feat)[i];
        hb[i] = pack_bf2(v.x, v.y);
        return;
    }
    __shared__ int hist[NBKT];
    __shared__ int cbase[NBKT];
    int tile = blockIdx.x * TILE_E;
    for (int i = t; i < NBKT; i += 256) hist[i] = 0;
    __syncthreads();
    int r[16], c[16], pos[16];
    #pragma unroll
    for (int k = 0; k < 16; k++) {
        int e = tile + k * 256 + t;
        if (e < N_EDGES) {
            r[k] = row[e]; c[k] = col[e];
            pos[k] = atomicAdd(&hist[r[k] / RPB], 1);
        } else r[k] = -1;
    }
    __syncthreads();
    for (int i = t; i < NBKT; i += 256) {
        int h = hist[i];
        cbase[i] = h ? atomicAdd(&bktsz[i], h) : 0;
    }
    __syncthreads();
    #pragma unroll
    for (int k = 0; k < 16; k++) {
        if (r[k] >= 0) {
            int b = r[k] / RPB;
            int slot = cbase[b] + pos[k];
            if (slot < BCAP)   // statistically impossible overflow guard
                csr_tmp[b * BCAP + slot] = ((r[k] & (RPB - 1)) << 17) | c[k];
        }
    }
}

// ---- refine A: per bucket, fine histogram + local scan -> rowinfo/dinv/selfc
__global__ __launch_bounds__(256) void refineA_k(const int* __restrict__ csr_tmp,
                                                 const int* __restrict__ bktsz,
                                                 int2* __restrict__ rowinfo,
                                                 float* __restrict__ dinv,
                                                 float* __restrict__ selfc) {
    __shared__ int hist[RPB];
    __shared__ int psc[RPB];
    int b = blockIdx.x, t = threadIdx.x;
    int r0 = b * RPB;
    int nrows = min(RPB, N_NODES - r0);
    hist[t] = 0;
    __syncthreads();
    int cnt = bktsz[b];
    const int* base = csr_tmp + b * BCAP;
    for (int i = t; i < cnt; i += 256)
        atomicAdd(&hist[base[i] >> 17], 1);
    __syncthreads();
    int v = hist[t];
    psc[t] = v;
    __syncthreads();
    for (int off = 1; off < 256; off <<= 1) {
        int x = (t >= off) ? psc[t - off] : 0;
        __syncthreads();
        psc[t] += x;
        __syncthreads();
    }
    if (t < nrows) {
        int start = b * BCAP + psc[t] - v;     // exclusive prefix, bucket-local
        float d = rsqrtf((float)v + 1.0f);
        rowinfo[r0 + t] = make_int2(start, start + v);
        dinv[r0 + t]  = d;
        selfc[r0 + t] = 0.5f + 0.5f * d * d;
    }
}

// ---- refine B: scatter edges to final CSR with full weight ----
__global__ __launch_bounds__(256) void refineB_k(const int* __restrict__ csr_tmp,
                                                 const int* __restrict__ bktsz,
                                                 const int2* __restrict__ rowinfo,
                                                 const float* __restrict__ dinv,
                                                 int2* __restrict__ csr) {
    __shared__ int   cur[RPB];
    __shared__ float dl[RPB];
    int b = blockIdx.x, t = threadIdx.x;
    int r0 = b * RPB;
    int nrows = min(RPB, N_NODES - r0);
    if (t < nrows) {
        cur[t] = rowinfo[r0 + t].x;
        dl[t]  = dinv[r0 + t];
    }
    __syncthreads();
    int cnt = bktsz[b];
    const int* base = csr_tmp + b * BCAP;
    for (int i = t; i < cnt; i += 256) {
        int pk = base[i];
        int lr = pk >> 17;
        int c  = pk & 0x1FFFF;
        int p = atomicAdd(&cur[lr], 1);
        float w = (0.5f * dl[lr]) * dinv[c];
        csr[p] = make_int2(c, __float_as_int(w));
    }
}

// ---- propagation: one wave per node, 4 lane-groups x 16 lanes ----
// group g handles edge j+g; lane (g,s) loads row segment s as uint4 (16B).
// Per 4-edge batch one global_load_dwordx4 moves 1KB (vs 256B with dwords).
__global__ __launch_bounds__(256) void prop_bf_k(const unsigned* __restrict__ hin,
                                                 unsigned* __restrict__ hout,
                                                 const int2* __restrict__ rowinfo,
                                                 const int2* __restrict__ csr,
                                                 const float* __restrict__ selfc) {
    int wave = threadIdx.x >> 6, lane = threadIdx.x & 63;
    int node = blockIdx.x * 4 + wave;     // N % 4 == 0
    int g = lane >> 4, s = lane & 15;
    const uint4* h4 = (const uint4*)hin;  // one row = 16 uint4
    int2 ri = rowinfo[node];
    int start = __builtin_amdgcn_readfirstlane(ri.x);
    int end   = __builtin_amdgcn_readfirstlane(ri.y);

    float a0 = 0.f, a1 = 0.f, a2 = 0.f, a3 = 0.f;
    float a4 = 0.f, a5 = 0.f, a6 = 0.f, a7 = 0.f;

    for (int j = start; j < end; j += 16) {
        // 4 masked sub-batches of 4 edges -> 4 dwordx4 gathers in flight
        int  i0 = j + g, i1 = j + 4 + g, i2 = j + 8 + g, i3 = j + 12 + g;
        int2 e0 = (i0 < end) ? csr[i0] : make_int2(0, 0);
        int2 e1 = (i1 < end) ? csr[i1] : make_int2(0, 0);
        int2 e2 = (i2 < end) ? csr[i2] : make_int2(0, 0);
        int2 e3 = (i3 < end) ? csr[i3] : make_int2(0, 0);
        uint4 v0 = h4[(unsigned)e0.x * 16 + s];
        uint4 v1 = h4[(unsigned)e1.x * 16 + s];
        uint4 v2 = h4[(unsigned)e2.x * 16 + s];
        uint4 v3 = h4[(unsigned)e3.x * 16 + s];
        float w0 = __int_as_float(e0.y);
        float w1 = __int_as_float(e1.y);
        float w2 = __int_as_float(e2.y);
        float w3 = __int_as_float(e3.y);
        a0 += w0 * bf_lo(v0.x); a1 += w0 * bf_hi(v0.x);
        a2 += w0 * bf_lo(v0.y); a3 += w0 * bf_hi(v0.y);
        a4 += w0 * bf_lo(v0.z); a5 += w0 * bf_hi(v0.z);
        a6 += w0 * bf_lo(v0.w); a7 += w0 * bf_hi(v0.w);
        a0 += w1 * bf_lo(v1.x); a1 += w1 * bf_hi(v1.x);
        a2 += w1 * bf_lo(v1.y); a3 += w1 * bf_hi(v1.y);
        a4 += w1 * bf_lo(v1.z); a5 += w1 * bf_hi(v1.z);
        a6 += w1 * bf_lo(v1.w); a7 += w1 * bf_hi(v1.w);
        a0 += w2 * bf_lo(v2.x); a1 += w2 * bf_hi(v2.x);
        a2 += w2 * bf_lo(v2.y); a3 += w2 * bf_hi(v2.y);
        a4 += w2 * bf_lo(v2.z); a5 += w2 * bf_hi(v2.z);
        a6 += w2 * bf_lo(v2.w); a7 += w2 * bf_hi(v2.w);
        a0 += w3 * bf_lo(v3.x); a1 += w3 * bf_hi(v3.x);
        a2 += w3 * bf_lo(v3.y); a3 += w3 * bf_hi(v3.y);
        a4 += w3 * bf_lo(v3.z); a5 += w3 * bf_hi(v3.z);
        a6 += w3 * bf_lo(v3.w); a7 += w3 * bf_hi(v3.w);
    }

    // fold the 4 lane-groups
    a0 += __shfl_xor(a0, 16); a0 += __shfl_xor(a0, 32);
    a1 += __shfl_xor(a1, 16); a1 += __shfl_xor(a1, 32);
    a2 += __shfl_xor(a2, 16); a2 += __shfl_xor(a2, 32);
    a3 += __shfl_xor(a3, 16); a3 += __shfl_xor(a3, 32);
    a4 += __shfl_xor(a4, 16); a4 += __shfl_xor(a4, 32);
    a5 += __shfl_xor(a5, 16); a5 += __shfl_xor(a5, 32);
    a6 += __shfl_xor(a6, 16); a6 += __shfl_xor(a6, 32);
    a7 += __shfl_xor(a7, 16); a7 += __shfl_xor(a7, 32);

    // self term + pack + store (group 0 only)
    if (g == 0) {
        uint4 own = h4[node * 16 + s];
        float sc = selfc[node];
        a0 += sc * bf_lo(own.x); a1 += sc * bf_hi(own.x);
        a2 += sc * bf_lo(own.y); a3 += sc * bf_hi(own.y);
        a4 += sc * bf_lo(own.z); a5 += sc * bf_hi(own.z);
        a6 += sc * bf_lo(own.w); a7 += sc * bf_hi(own.w);
        uint4 o;
        o.x = pack_bf2(a0, a1);
        o.y = pack_bf2(a2, a3);
        o.z = pack_bf2(a4, a5);
        o.w = pack_bf2(a6, a7);
        ((uint4*)hout)[node * 16 + s] = o;
    }
}

// ---- fused fc + LayerNorm via MFMA: one wave per 16-node tile ----
__global__ __launch_bounds__(256) void fcln_mfma_k(const unsigned* __restrict__ h,
                                                   const float* __restrict__ W,
                                                   const float* __restrict__ b,
                                                   const float* __restrict__ gamma,
                                                   const float* __restrict__ beta,
                                                   float* __restrict__ out) {
    int t = threadIdx.x;
    int wave = t >> 6, lane = t & 63;
    int m = lane & 15, quad = lane >> 4;
    int tile = blockIdx.x * 4 + wave;
    if (tile * 16 >= N_NODES) return;
    int node0 = tile * 16;

    short8 bfrag[3][4];
    float bias[3], gam[3], bet[3];
    #pragma unroll
    for (int ct = 0; ct < 3; ct++) {
        int c = ct * 16 + m;
        bool ok = (c < C_CLS);
        bias[ct] = ok ? b[c] : 0.0f;
        gam[ct]  = ok ? gamma[c] : 0.0f;
        bet[ct]  = ok ? beta[c] : 0.0f;
        #pragma unroll
        for (int ks = 0; ks < 4; ks++) {
            const float* wr = W + c * D_FEAT + ks * 32 + quad * 8;
            #pragma unroll
            for (int j = 0; j < 8; j++)
                bfrag[ct][ks][j] = ok ? bf16_of(wr[j]) : (short)0;
        }
    }

    floatx4 acc0 = {0.f,0.f,0.f,0.f}, acc1 = acc0, acc2 = acc0;
    #pragma unroll
    for (int ks = 0; ks < 4; ks++) {
        const uint4* ap = (const uint4*)&h[(node0 + m) * 64 + ks * 16 + quad * 4];
        uint4 araw = *ap;
        short8 afrag;
        afrag[0] = (short)(araw.x & 0xffff); afrag[1] = (short)(araw.x >> 16);
        afrag[2] = (short)(araw.y & 0xffff); afrag[3] = (short)(araw.y >> 16);
        afrag[4] = (short)(araw.z & 0xffff); afrag[5] = (short)(araw.z >> 16);
        afrag[6] = (short)(araw.w & 0xffff); afrag[7] = (short)(araw.w >> 16);
        acc0 = __builtin_amdgcn_mfma_f32_16x16x32_bf16(afrag, bfrag[0][ks], acc0, 0, 0, 0);
        acc1 = __builtin_amdgcn_mfma_f32_16x16x32_bf16(afrag, bfrag[1][ks], acc1, 0, 0, 0);
        acc2 = __builtin_amdgcn_mfma_f32_16x16x32_bf16(afrag, bfrag[2][ks], acc2, 0, 0, 0);
    }

    #pragma unroll
    for (int r = 0; r < 4; r++) { acc0[r] += bias[0]; acc1[r] += bias[1]; acc2[r] += bias[2]; }

    float s[4], ss[4];
    #pragma unroll
    for (int r = 0; r < 4; r++) {
        s[r]  = acc0[r] + acc1[r] + acc2[r];
        ss[r] = acc0[r]*acc0[r] + acc1[r]*acc1[r] + acc2[r]*acc2[r];
    }
    #pragma unroll
    for (int o = 1; o < 16; o <<= 1) {
        #pragma unroll
        for (int r = 0; r < 4; r++) {
            s[r]  += __shfl_xor(s[r], o);
            ss[r] += __shfl_xor(ss[r], o);
        }
    }

    #pragma unroll
    for (int r = 0; r < 4; r++) {
        int node = node0 + quad * 4 + r;
        float mean = s[r] * (1.0f / C_CLS);
        float var  = ss[r] * (1.0f / C_CLS) - mean * mean;
        float inv  = rsqrtf(var + LN_EPS);
        float* orow = out + (size_t)node * C_CLS;
        orow[m]      = (acc0[r] - mean) * inv * gam[0] + bet[0];
        orow[16 + m] = (acc1[r] - mean) * inv * gam[1] + bet[1];
        if (m < 8)
            orow[32 + m] = (acc2[r] - mean) * inv * gam[2] + bet[2];
    }
}

// ---------------- launch ----------------
extern "C" void kernel_launch(void* const* d_in, const int* in_sizes, int n_in,
                              void* d_out, int out_size, void* d_ws, size_t ws_size,
                              hipStream_t stream) {
    const float* feat  = (const float*)d_in[0];
    const int*   row   = (const int*)d_in[1];
    const int*   col   = (const int*)d_in[2];
    const float* W     = (const float*)d_in[3];
    const float* b     = (const float*)d_in[4];
    const float* gamma = (const float*)d_in[5];
    const float* beta  = (const float*)d_in[6];
    float* out = (float*)d_out;

    char* ws = (char*)d_ws;
    size_t off = 0;
    auto alloc = [&](size_t bytes) {
        size_t o = off;
        off = (off + bytes + 255) & ~(size_t)255;
        return o;
    };
    float*    dinv     = (float*)   (ws + alloc((size_t)N_NODES * 4));
    float*    selfc    = (float*)   (ws + alloc((size_t)N_NODES * 4));
    int2*     rowinfo  = (int2*)    (ws + alloc((size_t)N_NODES * 8));
    int*      bktsz    = (int*)     (ws + alloc((size_t)NBKT * 4));
    int*      csr_tmp  = (int*)     (ws + alloc((size_t)NBKT * BCAP * 4));
    int2*     csr      = (int2*)    (ws + alloc((size_t)NBKT * BCAP * 8));
    unsigned* h0       = (unsigned*)(ws + alloc((size_t)N_NODES * 64 * 4));
    unsigned* h1       = (unsigned*)(ws + alloc((size_t)N_NODES * 64 * 4));

    hipMemsetAsync(bktsz, 0, (size_t)NBKT * 4, stream);

    convbin_k<<<EBLK + CONVB, 256, 0, stream>>>(feat, h0, row, col, bktsz, csr_tmp);
    refineA_k<<<NBKT, 256, 0, stream>>>(csr_tmp, bktsz, rowinfo, dinv, selfc);
    refineB_k<<<NBKT, 256, 0, stream>>>(csr_tmp, bktsz, rowinfo, dinv, csr);

    int pgrid = N_NODES / 4;
    prop_bf_k<<<pgrid, 256, 0, stream>>>(h0, h1, rowinfo, csr, selfc);
    prop_bf_k<<<pgrid, 256, 0, stream>>>(h1, h0, rowinfo, csr, selfc);
    prop_bf_k<<<pgrid, 256, 0, stream>>>(h0, h1, rowinfo, csr, selfc);
    prop_bf_k<<<pgrid, 256, 0, stream>>>(h1, h0, rowinfo, csr, selfc);

    int tiles = N_NODES / 16;                       // 6250
    int fblocks = (tiles + 3) / 4;                  // 1563
    fcln_mfma_k<<<fblocks, 256, 0, stream>>>(h0, W, b, gamma, beta, out);
}